// Round 2
// baseline (454.686 us; speedup 1.0000x reference)
//
#include <hip/hip_runtime.h>

// RetNet retention (diagonal state): per-channel linear scan over S.
// B=4, S=4096, D=2048, H=16, hd=128. fp32 in/out.
//
// Two-pass chunked scan, round 2: explicit batch-of-8 register loads for MLP
// (R1 was latency-bound: VGPR=28, ~1.4 TB/s, VALUBusy 2%), C=128 chunks for
// 16 waves/CU occupancy.

namespace {

constexpr int kBlk  = 256;
constexpr int kB    = 4;
constexpr int kS    = 4096;
constexpr int kD    = 2048;
constexpr int kRow  = kD / 4;        // 512 float4 per (b,s) row
constexpr int kNG   = kB * kRow;     // 2048 float4-groups (b, j4)
constexpr int kC    = 128;           // chunks over S
constexpr int kL    = kS / kC;       // 32 steps per chunk
constexpr int kBatch = 8;            // time steps loaded per burst

__device__ __forceinline__ void fma4(float4& r, float d, const float4& a) {
  r.x = fmaf(d, r.x, a.x);
  r.y = fmaf(d, r.y, a.y);
  r.z = fmaf(d, r.z, a.z);
  r.w = fmaf(d, r.w, a.w);
}

__global__ __launch_bounds__(kBlk) void chunk_state_kernel(
    const float4* __restrict__ k, const float4* __restrict__ v,
    const float* __restrict__ decay, float4* __restrict__ A) {
  const int tid = blockIdx.x * kBlk + threadIdx.x;   // [0, kNG*kC)
  const int g   = tid & (kNG - 1);
  const int c   = tid >> 11;                          // tid / kNG
  const int b   = g >> 9;                             // g / kRow
  const int j4  = g & (kRow - 1);
  const int h   = j4 >> 5;                            // (j4*4)/128
  const float d = decay[h];

  const int base = (b * kS + c * kL) * kRow + j4;     // float4 index
  float4 r = make_float4(0.f, 0.f, 0.f, 0.f);
  for (int t0 = 0; t0 < kL; t0 += kBatch) {
    float4 K[kBatch], V[kBatch];
#pragma unroll
    for (int i = 0; i < kBatch; ++i) {
      K[i] = k[base + (t0 + i) * kRow];
      V[i] = v[base + (t0 + i) * kRow];
    }
#pragma unroll
    for (int i = 0; i < kBatch; ++i) {
      float4 kv;
      kv.x = K[i].x * V[i].x;
      kv.y = K[i].y * V[i].y;
      kv.z = K[i].z * V[i].z;
      kv.w = K[i].w * V[i].w;
      fma4(r, d, kv);
    }
  }
  A[c * kNG + g] = r;
}

__global__ __launch_bounds__(kBlk) void retention_out_kernel(
    const float4* __restrict__ q, const float4* __restrict__ k,
    const float4* __restrict__ v, const float* __restrict__ decay,
    const float4* __restrict__ A, float4* __restrict__ out) {
  const int tid = blockIdx.x * kBlk + threadIdx.x;
  const int g   = tid & (kNG - 1);
  const int c   = tid >> 11;
  const int b   = g >> 9;
  const int j4  = g & (kRow - 1);
  const int h   = j4 >> 5;
  const float d = decay[h];

  // d^L via 5 squarings (L = 32 = 2^5)
  float dL = d;
#pragma unroll
  for (int t = 0; t < 5; ++t) dL *= dL;

  // carry = state at end of chunk c-1 = scan of A[0..c-1] with factor d^L.
  // Wave-uniform c (2048 threads/chunk, 256/block); A is L2-resident (4 MiB).
  float4 r = make_float4(0.f, 0.f, 0.f, 0.f);
  int cc = 0;
  for (; cc + kBatch <= c; cc += kBatch) {
    float4 a[kBatch];
#pragma unroll
    for (int i = 0; i < kBatch; ++i) a[i] = A[(cc + i) * kNG + g];
#pragma unroll
    for (int i = 0; i < kBatch; ++i) fma4(r, dL, a[i]);
  }
  for (; cc < c; ++cc) {
    float4 a = A[cc * kNG + g];
    fma4(r, dL, a);
  }

  const int base = (b * kS + c * kL) * kRow + j4;
  for (int t0 = 0; t0 < kL; t0 += kBatch) {
    float4 Q[kBatch], K[kBatch], V[kBatch];
#pragma unroll
    for (int i = 0; i < kBatch; ++i) {
      Q[i] = q[base + (t0 + i) * kRow];
      K[i] = k[base + (t0 + i) * kRow];
      V[i] = v[base + (t0 + i) * kRow];
    }
#pragma unroll
    for (int i = 0; i < kBatch; ++i) {
      float4 kv;
      kv.x = K[i].x * V[i].x;
      kv.y = K[i].y * V[i].y;
      kv.z = K[i].z * V[i].z;
      kv.w = K[i].w * V[i].w;
      fma4(r, d, kv);
      float4 o;
      o.x = Q[i].x * r.x;
      o.y = Q[i].y * r.y;
      o.z = Q[i].z * r.z;
      o.w = Q[i].w * r.w;
      out[base + (t0 + i) * kRow] = o;
    }
  }
}

}  // namespace

extern "C" void kernel_launch(void* const* d_in, const int* in_sizes, int n_in,
                              void* d_out, int out_size, void* d_ws, size_t ws_size,
                              hipStream_t stream) {
  const float4* q     = (const float4*)d_in[0];
  const float4* k     = (const float4*)d_in[1];
  const float4* v     = (const float4*)d_in[2];
  const float*  decay = (const float*)d_in[3];
  float4* out = (float4*)d_out;
  float4* A   = (float4*)d_ws;   // kC * kNG float4 = 4 MiB

  const int nthreads = kNG * kC;           // 262144
  const int nblocks  = nthreads / kBlk;    // 1024

  chunk_state_kernel<<<nblocks, kBlk, 0, stream>>>(k, v, decay, A);
  retention_out_kernel<<<nblocks, kBlk, 0, stream>>>(q, k, v, decay, A, out);
}